// Round 5
// baseline (3752.494 us; speedup 1.0000x reference)
//
#include <hip/hip_runtime.h>
#include <stdint.h>

#define BB 512
#define TT 512
#define FF 128
#define UU 256

typedef float f32x4 __attribute__((ext_vector_type(4)));
typedef short short8 __attribute__((ext_vector_type(8)));
typedef int int4v __attribute__((ext_vector_type(4)));
typedef float float4v __attribute__((ext_vector_type(4)));
typedef unsigned short ushort4v __attribute__((ext_vector_type(4)));

__device__ __forceinline__ unsigned short f2bf(float f) {
  union { float f; uint32_t u; } v; v.f = f;
  uint32_t u = v.u;
  u += 0x7fffu + ((u >> 16) & 1u);
  return (unsigned short)(u >> 16);
}
__device__ __forceinline__ float fast_rcp(float x) { return __builtin_amdgcn_rcpf(x); }
__device__ __forceinline__ float sigmoidf_(float x) { return fast_rcp(1.f + __expf(-x)); }
__device__ __forceinline__ float tanhf_(float x) { return 1.f - 2.f * fast_rcp(1.f + __expf(2.f * x)); }

// ---- prep: W^T combined [1024 cols][384 k] bf16, Wo^T [32][256] bf16, zero xchg --------
__global__ void prep_w(const float* __restrict__ Wx, const float* __restrict__ Wh,
                       const float* __restrict__ Wo,
                       unsigned short* __restrict__ Wt, unsigned short* __restrict__ Wot,
                       int* __restrict__ xchg) {
  int bidx = blockIdx.x;
  int tid = threadIdx.x; // 384
  if (bidx < 1024) {
    int n = bidx, k = tid;
    float v = (k < FF) ? Wx[(size_t)k * 1024 + n] : Wh[(size_t)(k - FF) * 1024 + n];
    Wt[(size_t)n * 384 + k] = f2bf(v);
  } else if (bidx == 1024) {
    for (int i = tid; i < 32 * 256; i += 384) {
      int o = i >> 8, u = i & 255;
      Wot[o * 256 + u] = f2bf(Wo[(size_t)u * 32 + o]);
    }
  } else {
    // zero both exchange buffers (2 * 262144 dwords); kernel-end writeback publishes
    int base = (bidx - 1025) * 2048;
    for (int i = tid; i < 2048; i += 384) xchg[base + i] = 0;
  }
}

// ---- x f32 -> bf16 ----------------------------------------------------------------------
__global__ void conv_x(const float* __restrict__ xf, unsigned short* __restrict__ xb) {
  size_t i = (size_t)blockIdx.x * 1024 + (size_t)threadIdx.x * 4;
  float4v v = *(const float4v*)(xf + i);
  ushort4v o;
  o.x = f2bf(v.x); o.y = f2bf(v.y); o.z = f2bf(v.z); o.w = f2bf(v.w);
  *(ushort4v*)(xb + i) = o;
}

__device__ __forceinline__ short8 load_xfrag(const unsigned short* p) {
  return *(const short8*)p;
}
__device__ __forceinline__ short8 load_xfrag(const float* p) {
  float4v lo = *(const float4v*)p;
  float4v hi = *(const float4v*)(p + 4);
  union { short8 v; unsigned short s[8]; } a;
  a.s[0] = f2bf(lo.x); a.s[1] = f2bf(lo.y); a.s[2] = f2bf(lo.z); a.s[3] = f2bf(lo.w);
  a.s[4] = f2bf(hi.x); a.s[5] = f2bf(hi.y); a.s[6] = f2bf(hi.z); a.s[7] = f2bf(hi.w);
  return a.v;
}

// 4x dwordx4 tagged-tile probe: offsets 0,16,128,144 bytes (= dwords 0..7 and 32..39)
__device__ __forceinline__ void xload4_l2(const int* p, int4v& a0, int4v& a1, int4v& a2, int4v& a3) {
  asm volatile(
      "global_load_dwordx4 %0, %4, off sc0\n\t"
      "global_load_dwordx4 %1, %4, off offset:16 sc0\n\t"
      "global_load_dwordx4 %2, %4, off offset:128 sc0\n\t"
      "global_load_dwordx4 %3, %4, off offset:144 sc0\n\t"
      "s_waitcnt vmcnt(0)"
      : "=&v"(a0), "=&v"(a1), "=&v"(a2), "=&v"(a3) : "v"(p) : "memory");
}
__device__ __forceinline__ void xload4_mall(const int* p, int4v& a0, int4v& a1, int4v& a2, int4v& a3) {
  asm volatile(
      "global_load_dwordx4 %0, %4, off sc0 sc1\n\t"
      "global_load_dwordx4 %1, %4, off offset:16 sc0 sc1\n\t"
      "global_load_dwordx4 %2, %4, off offset:128 sc0 sc1\n\t"
      "global_load_dwordx4 %3, %4, off offset:144 sc0 sc1\n\t"
      "s_waitcnt vmcnt(0)"
      : "=&v"(a0), "=&v"(a1), "=&v"(a2), "=&v"(a3) : "v"(p) : "memory");
}
__device__ __forceinline__ void store_sc0(int* p, int v) {
  asm volatile("global_store_dword %0, %1, off sc0" :: "v"(p), "v"(v) : "memory");
}
__device__ __forceinline__ void store_sc01(int* p, int v) {
  asm volatile("global_store_dword %0, %1, off sc0 sc1" :: "v"(p), "v"(v) : "memory");
}
__device__ __forceinline__ int tags_ok(const int4v& a0, const int4v& a1,
                                       const int4v& a2, const int4v& a3, int t) {
  int m = (a0.x ^ t) | (a0.y ^ t) | (a0.z ^ t) | (a0.w ^ t)
        | (a1.x ^ t) | (a1.y ^ t) | (a1.z ^ t) | (a1.w ^ t)
        | (a2.x ^ t) | (a2.y ^ t) | (a2.z ^ t) | (a2.w ^ t)
        | (a3.x ^ t) | (a3.y ^ t) | (a3.z ^ t) | (a3.w ^ t);
  return (m & 0xffff) == 0;
}
__device__ __forceinline__ uint32_t pk2(int lo, int hi) {
  return ((uint32_t)lo >> 16) | ((uint32_t)hi & 0xffff0000u);
}

// ---- recurrent core ---------------------------------------------------------------------
// xchg tile layout (per path): dword idx = ((mt*2 + side)*2 + slot)*2048 + row*128 + u_local
template <int HALF, typename XT>
__device__ __forceinline__ void lstm_core(const XT* __restrict__ x,
                                          const unsigned short* __restrict__ Wt,
                                          const float* __restrict__ bvec,
                                          unsigned short* __restrict__ h_hist,
                                          int* __restrict__ xl2, int* __restrict__ xmall,
                                          int bid, char* lds) {
  const int mt = bid & 31;
  const int tid = threadIdx.x;
  const int w = tid >> 6, l = tid & 63;
  const int lr = l & 15, lhi = l >> 4;
  const int b0 = mt * 16;
  const int uloc = HALF * 128 + w * 16 + lr;

  short8 Bf[4][12];
#pragma unroll
  for (int g = 0; g < 4; ++g) {
    const unsigned short* wp = Wt + (size_t)(g * 256 + uloc) * 384 + 8 * lhi;
#pragma unroll
    for (int k = 0; k < 12; ++k) Bf[g][k] = *(const short8*)(wp + k * 32);
  }
  float bias[4];
#pragma unroll
  for (int g = 0; g < 4; ++g) bias[g] = bvec[g * 256 + uloc];
  float cst[4] = {0.f, 0.f, 0.f, 0.f};

  constexpr int ko_own = 4 + HALF * 4;
  constexpr int ko_par = 4 + (1 - HALF) * 4;

  const int rtile = (mt * 2 + (1 - HALF)) * 2;  // + slot
  const int wtile = (mt * 2 + HALF) * 2;
  const int roff = lr * 128 + 8 * lhi;
  const int woff = w * 16 + lr;

  // prologue x prefetch
  short8 xa[4];
  {
    const XT* xp = x + ((size_t)(b0 + lr) * TT + 0) * FF + 8 * lhi;
#pragma unroll
    for (int kk = 0; kk < 4; ++kk) xa[kk] = load_xfrag(xp + kk * 32);
  }

#pragma unroll 1
  for (int t = 0; t < TT; ++t) {
    const int cur = t & 1, nxt = cur ^ 1;

    f32x4 acc[4];
#pragma unroll
    for (int g = 0; g < 4; ++g) { f32x4 a4 = {bias[g], bias[g], bias[g], bias[g]}; acc[g] = a4; }

    if (t > 0) {
      // own-half h(t) from LDS double buffer
      short8 ho[4];
#pragma unroll
      for (int ko = 0; ko < 4; ++ko) {
        int byte = cur * 4096 + lr * 256 + ((ko * 64 + lhi * 16) ^ ((lr & 7) << 4));
        ho[ko] = *(const short8*)(lds + byte);
      }
#pragma unroll
      for (int ko = 0; ko < 4; ++ko)
#pragma unroll
        for (int g = 0; g < 4; ++g)
          acc[g] = __builtin_amdgcn_mfma_f32_16x16x32_bf16(ho[ko], Bf[g][ko_own + ko], acc[g], 0, 0, 0);
    }

    // x-part MFMAs
#pragma unroll
    for (int kk = 0; kk < 4; ++kk)
#pragma unroll
      for (int g = 0; g < 4; ++g)
        acc[g] = __builtin_amdgcn_mfma_f32_16x16x32_bf16(xa[kk], Bf[g][kk], acc[g], 0, 0, 0);

    // x prefetch for t+1 (plain cached loads; overlaps the partner poll below)
    {
      const int tn = (t + 1 < TT) ? t + 1 : t;
      const XT* xp = x + ((size_t)(b0 + lr) * TT + tn) * FF + 8 * lhi;
#pragma unroll
      for (int kk = 0; kk < 4; ++kk) xa[kk] = load_xfrag(xp + kk * 32);
    }

    if (t > 0) {
      const int rbase = (rtile + (t & 1)) * 2048 + roff;
      const int* pLb = xl2 + rbase;
      const int* pMb = xmall + rbase;
#pragma unroll
      for (int kfh = 0; kfh < 2; ++kfh) {
        const int* pL = pLb + kfh * 64;
        const int* pM = pMb + kfh * 64;
        int4v a0, a1, a2, a3;
        xload4_l2(pL, a0, a1, a2, a3);
        while (!__all(tags_ok(a0, a1, a2, a3, t))) {
          xload4_mall(pM, a0, a1, a2, a3);
          if (__all(tags_ok(a0, a1, a2, a3, t))) break;
          xload4_l2(pL, a0, a1, a2, a3);
        }
        __builtin_amdgcn_sched_barrier(0);
        int4v k0, k1;
        k0.x = pk2(a0.x, a0.y); k0.y = pk2(a0.z, a0.w);
        k0.z = pk2(a1.x, a1.y); k0.w = pk2(a1.z, a1.w);
        k1.x = pk2(a2.x, a2.y); k1.y = pk2(a2.z, a2.w);
        k1.z = pk2(a3.x, a3.y); k1.w = pk2(a3.z, a3.w);
        short8 f0 = __builtin_bit_cast(short8, k0);
        short8 f1 = __builtin_bit_cast(short8, k1);
#pragma unroll
        for (int g = 0; g < 4; ++g)
          acc[g] = __builtin_amdgcn_mfma_f32_16x16x32_bf16(f0, Bf[g][ko_par + kfh * 2 + 0], acc[g], 0, 0, 0);
#pragma unroll
        for (int g = 0; g < 4; ++g)
          acc[g] = __builtin_amdgcn_mfma_f32_16x16x32_bf16(f1, Bf[g][ko_par + kfh * 2 + 1], acc[g], 0, 0, 0);
      }
    }

    // gates
    unsigned short hs[4];
#pragma unroll
    for (int r = 0; r < 4; ++r) {
      float zi = acc[0][r], zf = acc[1][r], zg = acc[2][r], zo = acc[3][r];
      float si = sigmoidf_(zi), sf = sigmoidf_(zf), so = sigmoidf_(zo);
      float tg = tanhf_(zg);
      float cn = sf * cst[r] + si * tg;
      cst[r] = cn;
      hs[r] = f2bf(so * tanhf_(cn));
    }

    // publish h(t+1): tagged dual-path exchange + LDS own-half + cached h_hist (for y)
    const int wbase = (wtile + ((t + 1) & 1)) * 2048 + woff;
    unsigned short* hw = h_hist + (size_t)(t + 1) * (BB * UU) + uloc;
#pragma unroll
    for (int r = 0; r < 4; ++r) {
      const int row = 4 * lhi + r;
      const int tagged = ((int)(uint32_t)hs[r] << 16) | (t + 1);
      store_sc0(xl2 + wbase + row * 128, tagged);
      store_sc01(xmall + wbase + row * 128, tagged);
      const int byte = nxt * 4096 + row * 256 + (((w * 16 + lr) * 2) ^ ((row & 7) << 4));
      *(unsigned short*)(lds + byte) = hs[r];
      hw[(size_t)(b0 + row) * UU] = hs[r];
    }

    __syncthreads();
  }
}

template <typename XT>
__global__ void __launch_bounds__(512, 2)
lstm_main5(const XT* __restrict__ x, const unsigned short* __restrict__ Wt,
           const float* __restrict__ bvec, unsigned short* __restrict__ h_hist,
           int* __restrict__ xl2, int* __restrict__ xmall) {
  __shared__ __align__(16) char lds[8192];
  const int bid = blockIdx.x;
  if (bid < 32) lstm_core<0, XT>(x, Wt, bvec, h_hist, xl2, xmall, bid, lds);
  else          lstm_core<1, XT>(x, Wt, bvec, h_hist, xl2, xmall, bid, lds);
}

// ---- y = h @ Wo + bo --------------------------------------------------------------------
__global__ void __launch_bounds__(256)
y_gemm(const unsigned short* __restrict__ h_hist, const unsigned short* __restrict__ Wot,
       const float* __restrict__ bo, float* __restrict__ out) {
  int gw = (int)((blockIdx.x * 256 + threadIdx.x) >> 6);
  int l = threadIdx.x & 63;
  int lr = l & 15, lhi = l >> 4;
  int b = gw >> 5;
  int t0 = (gw & 31) * 16;

  short8 Wf[2][8];
#pragma unroll
  for (int n = 0; n < 2; ++n) {
    const unsigned short* wp = Wot + (n * 16 + lr) * 256 + 8 * lhi;
#pragma unroll
    for (int kk = 0; kk < 8; ++kk) Wf[n][kk] = *(const short8*)(wp + kk * 32);
  }
  f32x4 acc[2];
#pragma unroll
  for (int n = 0; n < 2; ++n) {
    float bb = bo[n * 16 + lr];
    f32x4 a4 = {bb, bb, bb, bb};
    acc[n] = a4;
  }
  const unsigned short* hp =
      h_hist + ((size_t)(t0 + lr + 1) * BB + b) * UU + 8 * lhi;
#pragma unroll
  for (int kk = 0; kk < 8; ++kk) {
    short8 a = *(const short8*)(hp + kk * 32);
#pragma unroll
    for (int n = 0; n < 2; ++n)
      acc[n] = __builtin_amdgcn_mfma_f32_16x16x32_bf16(a, Wf[n][kk], acc[n], 0, 0, 0);
  }
#pragma unroll
  for (int n = 0; n < 2; ++n) {
    int o = n * 16 + lr;
#pragma unroll
    for (int r = 0; r < 4; ++r) {
      int t = t0 + 4 * lhi + r;
      out[((size_t)b * TT + t) * 32 + o] = acc[n][r];
    }
  }
}

extern "C" void kernel_launch(void* const* d_in, const int* in_sizes, int n_in,
                              void* d_out, int out_size, void* d_ws, size_t ws_size,
                              hipStream_t stream) {
  const float* x  = (const float*)d_in[0];
  const float* Wx = (const float*)d_in[1];
  const float* Wh = (const float*)d_in[2];
  const float* bv = (const float*)d_in[3];
  const float* Wo = (const float*)d_in[4];
  const float* bo = (const float*)d_in[5];

  char* ws = (char*)d_ws;
  size_t off = 0;
  unsigned short* h_hist = (unsigned short*)(ws + off); off += (size_t)513 * BB * UU * 2; // 134.5 MB
  unsigned short* Wt384  = (unsigned short*)(ws + off); off += (size_t)1024 * 384 * 2;
  unsigned short* Wot    = (unsigned short*)(ws + off); off += (size_t)32 * 256 * 2;
  off = (off + 255) & ~(size_t)255;
  int* xl2   = (int*)(ws + off); off += (size_t)262144 * 4;  // 1 MB
  int* xmall = (int*)(ws + off); off += (size_t)262144 * 4;  // 1 MB
  off = (off + 255) & ~(size_t)255;
  unsigned short* xb = (unsigned short*)(ws + off);
  const size_t need_xb = off + (size_t)BB * TT * FF * 2;  // ~204 MB total

  prep_w<<<1281, 384, 0, stream>>>(Wx, Wh, Wo, Wt384, Wot, xl2);
  if (ws_size >= need_xb) {
    conv_x<<<32768, 256, 0, stream>>>(x, xb);
    lstm_main5<unsigned short><<<64, 512, 0, stream>>>(xb, Wt384, bv, h_hist, xl2, xmall);
  } else {
    lstm_main5<float><<<64, 512, 0, stream>>>(x, Wt384, bv, h_hist, xl2, xmall);
  }
  y_gemm<<<4096, 256, 0, stream>>>(h_hist, Wot, bo, (float*)d_out);
}